// Round 9
// baseline (158.275 us; speedup 1.0000x reference)
//
#include <hip/hip_runtime.h>
#include <math.h>

// QMIX mixing network, B=65536, A=8, S=256, E=32. All tensors fp32.
// Transposed MFMA: A-operand = bf16(Wcat^T) fragments (m = out col),
// B-operand = bf16(states) (n = batch row), mfma_f32_16x16x32_bf16.
// One 512-thread block per CU (grid 256, 256 rows/block, 32 rows/wave dual-B).
// All 16 w1 tiles (128 KB) staged ONCE into LDS via global_load_lds (single
// barrier); tiles 16..21 (6/chunk) stream from L2 into registers. The K-loop
// has no barriers and no LDS writes — 8 waves/CU hide latency by TLP.
// __launch_bounds__(512,1): R8's (512,2) compiled to a 128-reg budget and
// spilled acc (WRITE_SIZE 58 MB); (·,1) lets the allocator take ~240 regs,
// still 2 waves/SIMD at runtime (<=256).
// Wcat columns: [0,256)=w1_W, [256,288)=wf_W, [288,320)=b1_W, [320,352)=v1_W.

#define NTILES 22      // 352/16
#define KCHUNKS 8      // 256/32
#define LDS_SLOTS 128  // 16 w1-tiles x 8 chunks, 1 KB each

typedef __attribute__((ext_vector_type(8))) short short8;
typedef __attribute__((ext_vector_type(4))) float float4v;

__device__ __forceinline__ unsigned short f2b(float f) {
    unsigned int u = __float_as_uint(f);
    u = u + 0x7fffu + ((u >> 16) & 1u);   // RNE
    return (unsigned short)(u >> 16);
}

// Direct global->LDS DMA, 16 B/lane. LDS dest = wave-uniform base + lane*16.
__device__ __forceinline__ void gl2lds16(const unsigned short* g, unsigned short* l) {
    __builtin_amdgcn_global_load_lds(
        (const __attribute__((address_space(1))) unsigned int*)g,
        (__attribute__((address_space(3))) unsigned int*)l,
        16, 0, 0);
}

// Repack fp32 Wcat into bf16 A-fragment slots of 64 lanes x 16 B:
//   slot < 128:  slot = t*8 + kc   (t < 16: the w1 block -> contiguous 128 KB LDS image)
//   slot >= 128: slot = 128 + kc*6 + (t-16)   (per-chunk stream, 6 KB contiguous)
// brep[(slot*64 + lane)*8 + j] = bf16(Wcat[k = kc*32+(lane>>4)*8+j][t*16+(lane&15)])
__global__ void repack_b(const float* __restrict__ w1_W,
                         const float* __restrict__ wf_W,
                         const float* __restrict__ b1_W,
                         const float* __restrict__ v1_W,
                         unsigned short* __restrict__ brep) {
    int idx = blockIdx.x * 256 + threadIdx.x;   // 0..11263
    int lane = idx & 63;
    int slot = idx >> 6;          // 0..175
    int t, kc;
    if (slot < 128) { t = slot >> 3; kc = slot & 7; }
    else            { int r = slot - 128; kc = r / 6; t = 16 + r % 6; }
    int kbase = kc * 32 + (lane >> 4) * 8;
    int n = t * 16 + (lane & 15);
    short8 frag;
#pragma unroll
    for (int j = 0; j < 8; ++j) {
        int k = kbase + j;
        float val;
        if (n < 256)      val = w1_W[k * 256 + n];
        else if (n < 288) val = wf_W[k * 32 + (n - 256)];
        else if (n < 320) val = b1_W[k * 32 + (n - 288)];
        else              val = v1_W[k * 32 + (n - 320)];
        frag[j] = (short)f2b(val);
    }
    *(short8*)(&brep[idx * 8]) = frag;
}

__global__ void __launch_bounds__(512, 1)
qmix_main(const float* __restrict__ agent_qs,
          const float* __restrict__ states,
          const unsigned short* __restrict__ brep,
          const float* __restrict__ w1_b,
          const float* __restrict__ wf_b,
          const float* __restrict__ b1_b,
          const float* __restrict__ v1_b,
          const float* __restrict__ v2_W,
          const float* __restrict__ v2_b,
          float* __restrict__ out) {
    __shared__ __align__(16) unsigned short wlds[LDS_SLOTS * 64 * 8];   // 131072 B

    const int tid  = threadIdx.x;
    const int wave = tid >> 6, lane = tid & 63;
    const int quad = lane >> 4, l16 = lane & 15;
    const int r0 = blockIdx.x * 256 + wave * 32 + l16;   // group 0 row; group 1 = +16
    const float* srow0 = states + (size_t)r0 * 256;
    const float* srow1 = srow0 + 16 * 256;

    // ---- Stage all w1 slots (128 KB) into LDS once: 16 DMA instrs per wave ----
    for (int s = wave; s < LDS_SLOTS; s += 8)
        gl2lds16(brep + (size_t)(s * 64 + lane) * 8, wlds + s * 512);

    // ---- Preload states fragments for chunk 0 ----
    float4v s0a = *(const float4v*)(srow0 + quad * 8);
    float4v s0b = *(const float4v*)(srow0 + quad * 8 + 4);
    float4v s1a = *(const float4v*)(srow1 + quad * 8);
    float4v s1b = *(const float4v*)(srow1 + quad * 8 + 4);

    float4v acc[2][NTILES];
#pragma unroll
    for (int g = 0; g < 2; ++g)
#pragma unroll
        for (int t = 0; t < NTILES; ++t)
#pragma unroll
            for (int q = 0; q < 4; ++q) acc[g][t][q] = 0.f;

    __syncthreads();   // the ONLY barrier: w1 LDS image complete, read-only below

    const short8* wl = (const short8*)wlds + lane;                    // + (t*8+kc)*64
    const short8* ws = (const short8*)brep + LDS_SLOTS * 64 + lane;   // + (kc*6+u)*64

    for (int kc = 0; kc < KCHUNKS; ++kc) {
        // Stream this chunk's 6 non-w1 fragments from L2 (in flight during MFMAs)
        short8 sf[6];
#pragma unroll
        for (int u = 0; u < 6; ++u) sf[u] = ws[(kc * 6 + u) * 64];
        // Convert current states frags to bf16
        short8 b0, b1;
#pragma unroll
        for (int j = 0; j < 4; ++j) {
            b0[j] = (short)f2b(s0a[j]); b0[4 + j] = (short)f2b(s0b[j]);
            b1[j] = (short)f2b(s1a[j]); b1[4 + j] = (short)f2b(s1b[j]);
        }
        // Prefetch next states frags (VGPR pipeline, one chunk ahead)
        if (kc < KCHUNKS - 1) {
            const float* p0 = srow0 + (kc + 1) * 32 + quad * 8;
            const float* p1 = srow1 + (kc + 1) * 32 + quad * 8;
            s0a = *(const float4v*)(p0);
            s0b = *(const float4v*)(p0 + 4);
            s1a = *(const float4v*)(p1);
            s1b = *(const float4v*)(p1 + 4);
        }
        // w1 tiles from LDS: 16 ds_read_b128 feed 32 MFMAs
#pragma unroll
        for (int t = 0; t < 16; ++t) {
            short8 af = wl[(t * 8 + kc) * 64];
            acc[0][t] = __builtin_amdgcn_mfma_f32_16x16x32_bf16(af, b0, acc[0][t], 0, 0, 0);
            acc[1][t] = __builtin_amdgcn_mfma_f32_16x16x32_bf16(af, b1, acc[1][t], 0, 0, 0);
        }
        // streamed tiles 16..21: 12 MFMAs
#pragma unroll
        for (int u = 0; u < 6; ++u) {
            acc[0][16 + u] = __builtin_amdgcn_mfma_f32_16x16x32_bf16(sf[u], b0, acc[0][16 + u], 0, 0, 0);
            acc[1][16 + u] = __builtin_amdgcn_mfma_f32_16x16x32_bf16(sf[u], b1, acc[1][16 + u], 0, 0, 0);
        }
    }

    // ---- Epilogue (per row-group, all in registers; R4-R8 verified mapping) ----
#pragma unroll
    for (int g = 0; g < 2; ++g) {
        const int row = r0 + g * 16;
        float4v q0 = *(const float4v*)(agent_qs + (size_t)row * 8);
        float4v q1 = *(const float4v*)(agent_qs + (size_t)row * 8 + 4);
        float qv[8] = {q0[0], q0[1], q0[2], q0[3], q1[0], q1[1], q1[2], q1[3]};

        float qacc[8], wfv[8], b1v[8], svp = 0.f;
#pragma unroll
        for (int s = 0; s < 8; ++s) qacc[s] = 0.f;

#pragma unroll
        for (int t = 0; t < NTILES; ++t) {
            const float* bptr =
                (t < 16) ? (w1_b + t * 16) :
                (t < 18) ? (wf_b + (t - 16) * 16) :
                (t < 20) ? (b1_b + (t - 18) * 16) : (v1_b + (t - 20) * 16);
            float4v bb = *(const float4v*)(bptr + quad * 4);
            float vb[4];
#pragma unroll
            for (int j = 0; j < 4; ++j) vb[j] = acc[g][t][j] + bb[j];

            if (t < 16) {              // w1: agent a = t>>1, slot base = (t&1)*4
                float q = qv[t >> 1];
                int base = (t & 1) * 4;
#pragma unroll
                for (int j = 0; j < 4; ++j) qacc[base + j] += q * fabsf(vb[j]);
            } else if (t < 18) {       // w_final
                int base = (t - 16) * 4;
#pragma unroll
                for (int j = 0; j < 4; ++j) wfv[base + j] = fabsf(vb[j]);
            } else if (t < 20) {       // b1
                int base = (t - 18) * 4;
#pragma unroll
                for (int j = 0; j < 4; ++j) b1v[base + j] = vb[j];
            } else {                   // V hidden: relu -> dot v2_W
                int ebase = (t - 20) * 16 + quad * 4;
#pragma unroll
                for (int j = 0; j < 4; ++j)
                    svp += fmaxf(vb[j], 0.f) * v2_W[ebase + j];
            }
        }

        float mix = 0.f;
#pragma unroll
        for (int s = 0; s < 8; ++s) {
            float h = qacc[s] + b1v[s];
            h = h > 0.f ? h : (__expf(h) - 1.f);   // elu, alpha=1
            mix += h * wfv[s];
        }
        float tot = mix + svp;                      // partial over this quad's e-subset
        tot += __shfl_xor(tot, 16);                 // combine 4 quads (same batch row)
        tot += __shfl_xor(tot, 32);
        if (quad == 0) out[row] = tot + v2_b[0];
    }
}

extern "C" void kernel_launch(void* const* d_in, const int* in_sizes, int n_in,
                              void* d_out, int out_size, void* d_ws, size_t ws_size,
                              hipStream_t stream) {
    const float* agent_qs = (const float*)d_in[0];
    const float* states   = (const float*)d_in[1];
    const float* w1_W = (const float*)d_in[2];
    const float* w1_b = (const float*)d_in[3];
    const float* wf_W = (const float*)d_in[4];
    const float* wf_b = (const float*)d_in[5];
    const float* b1_W = (const float*)d_in[6];
    const float* b1_b = (const float*)d_in[7];
    const float* v1_W = (const float*)d_in[8];
    const float* v1_b = (const float*)d_in[9];
    const float* v2_W = (const float*)d_in[10];
    const float* v2_b = (const float*)d_in[11];
    float* out = (float*)d_out;
    unsigned short* brep = (unsigned short*)d_ws;    // 180224 B of scratch

    repack_b<<<44, 256, 0, stream>>>(w1_W, wf_W, b1_W, v1_W, brep);
    qmix_main<<<256, 512, 0, stream>>>(agent_qs, states, brep,
                                       w1_b, wf_b, b1_b, v1_b, v2_W, v2_b, out);
}

// Round 10
// 143.414 us; speedup vs baseline: 1.1036x; 1.1036x over previous
//
#include <hip/hip_runtime.h>
#include <math.h>

// QMIX mixing network, B=65536, A=8, S=256, E=32. All tensors fp32.
// Transposed MFMA: A-operand = bf16(Wcat^T) fragments (m = out col),
// B-operand = bf16(states) (n = batch row), mfma_f32_16x16x32_bf16.
// Single-B: 16 rows/wave, 64 rows per 256-thread block, grid 1024.
// Weights staged per k-chunk (22.5 KB) into double-buffered LDS via
// global_load_lds DMA, prefetched one chunk ahead; one barrier per chunk.
// __launch_bounds__(256,3): acc=88 keeps live set ~130 regs -> no spill,
// 3 blocks/CU co-resident (12 waves) to hide the per-chunk barrier drain
// (R6/R7 plateaued at ~35us with only 2 blocks/CU; R8/R9's 512-thread
// barrier-free variant spilled at the compiler's 128-reg cap — abandoned).
// Wcat columns: [0,256)=w1_W, [256,288)=wf_W, [288,320)=b1_W, [320,352)=v1_W.

#define NTILES 22      // 352/16
#define KCHUNKS 8      // 256/32
#define CHUNK_I4 1408  // 16B units per k-chunk (22528 B)

typedef __attribute__((ext_vector_type(8))) short short8;
typedef __attribute__((ext_vector_type(4))) float float4v;

__device__ __forceinline__ unsigned short f2b(float f) {
    unsigned int u = __float_as_uint(f);
    u = u + 0x7fffu + ((u >> 16) & 1u);   // RNE
    return (unsigned short)(u >> 16);
}

// Direct global->LDS DMA, 16 B/lane. LDS dest = wave-uniform base + lane*16.
__device__ __forceinline__ void gl2lds16(const unsigned short* g, unsigned short* l) {
    __builtin_amdgcn_global_load_lds(
        (const __attribute__((address_space(1))) unsigned int*)g,
        (__attribute__((address_space(3))) unsigned int*)l,
        16, 0, 0);
}

// Repack fp32 Wcat into bf16 A-fragment order, slot = kc*22 + t (kc-major:
// each k-chunk is a contiguous 22528 B block — validated R2-R7):
// brep[(slot*64 + lane)*8 + j] = bf16(Wcat[k = kc*32+(lane>>4)*8+j][t*16+(lane&15)])
__global__ void repack_b(const float* __restrict__ w1_W,
                         const float* __restrict__ wf_W,
                         const float* __restrict__ b1_W,
                         const float* __restrict__ v1_W,
                         unsigned short* __restrict__ brep) {
    int idx = blockIdx.x * 256 + threadIdx.x;   // 0..11263
    int lane = idx & 63;
    int tt   = idx >> 6;          // kc*22 + t
    int t    = tt % 22;
    int kc   = tt / 22;
    int kbase = kc * 32 + (lane >> 4) * 8;
    int n = t * 16 + (lane & 15);
    short8 frag;
#pragma unroll
    for (int j = 0; j < 8; ++j) {
        int k = kbase + j;
        float val;
        if (n < 256)      val = w1_W[k * 256 + n];
        else if (n < 288) val = wf_W[k * 32 + (n - 256)];
        else if (n < 320) val = b1_W[k * 32 + (n - 288)];
        else              val = v1_W[k * 32 + (n - 320)];
        frag[j] = (short)f2b(val);
    }
    *(short8*)(&brep[idx * 8]) = frag;
}

__global__ void __launch_bounds__(256, 3)
qmix_main(const float* __restrict__ agent_qs,
          const float* __restrict__ states,
          const unsigned short* __restrict__ brep,
          const float* __restrict__ w1_b,
          const float* __restrict__ wf_b,
          const float* __restrict__ b1_b,
          const float* __restrict__ v1_b,
          const float* __restrict__ v2_W,
          const float* __restrict__ v2_b,
          float* __restrict__ out) {
    __shared__ __align__(16) unsigned short wlds[2][NTILES * 64 * 8];  // 2 x 22528 B

    const int tid  = threadIdx.x;
    const int wave = tid >> 6, lane = tid & 63;
    const int quad = lane >> 4, l16 = lane & 15;
    const int row  = blockIdx.x * 64 + wave * 16 + l16;   // this wave's batch row (n)
    const float* srow = states + (size_t)row * 256;

    // ---- Stage chunk 0 into buffer 0 via DMA: slots 0..21, wave-strided ----
    for (int s = wave; s < NTILES; s += 4)
        gl2lds16(brep + (size_t)(s * 64 + lane) * 8, wlds[0] + s * 512);

    // ---- Preload states fragment for chunk 0 ----
    float4v s0a = *(const float4v*)(srow + quad * 8);
    float4v s0b = *(const float4v*)(srow + quad * 8 + 4);

    float4v acc[NTILES];
#pragma unroll
    for (int t = 0; t < NTILES; ++t)
#pragma unroll
        for (int q = 0; q < 4; ++q) acc[t][q] = 0.f;

    __syncthreads();   // drains chunk-0 DMA for all waves

    int cur = 0;
    for (int kc = 0; kc < KCHUNKS; ++kc) {
        // Prefetch next weight chunk straight into the other LDS buffer; the
        // DMA flies during this chunk's MFMA phase, drained at the barrier.
        if (kc < KCHUNKS - 1) {
            const unsigned short* src = brep + (size_t)(kc + 1) * CHUNK_I4 * 8;
            unsigned short* dst = wlds[cur ^ 1];
            for (int s = wave; s < NTILES; s += 4)
                gl2lds16(src + (size_t)(s * 64 + lane) * 8, dst + s * 512);
        }
        // Convert current states frag to bf16
        short8 b0;
#pragma unroll
        for (int j = 0; j < 4; ++j) {
            b0[j] = (short)f2b(s0a[j]); b0[4 + j] = (short)f2b(s0b[j]);
        }
        // Prefetch next states frag (VGPR pipeline, one chunk ahead)
        if (kc < KCHUNKS - 1) {
            const float* p0 = srow + (kc + 1) * 32 + quad * 8;
            s0a = *(const float4v*)(p0);
            s0b = *(const float4v*)(p0 + 4);
        }
        // MFMA phase on current buffer: 22 ds_read_b128 feed 22 MFMAs
        const short8* wb = (const short8*)wlds[cur] + lane;
#pragma unroll
        for (int t = 0; t < NTILES; ++t) {
            short8 af = wb[t * 64];
            acc[t] = __builtin_amdgcn_mfma_f32_16x16x32_bf16(af, b0, acc[t], 0, 0, 0);
        }
        cur ^= 1;
        __syncthreads();   // WAR on read buffer + drain of next chunk's DMA
    }

    // ---- Epilogue (all in registers; R4-R9 verified mapping) ----
    float4v q0 = *(const float4v*)(agent_qs + (size_t)row * 8);
    float4v q1 = *(const float4v*)(agent_qs + (size_t)row * 8 + 4);
    float qv[8] = {q0[0], q0[1], q0[2], q0[3], q1[0], q1[1], q1[2], q1[3]};

    float qacc[8], wfv[8], b1v[8], svp = 0.f;
#pragma unroll
    for (int s = 0; s < 8; ++s) qacc[s] = 0.f;

#pragma unroll
    for (int t = 0; t < NTILES; ++t) {
        const float* bptr =
            (t < 16) ? (w1_b + t * 16) :
            (t < 18) ? (wf_b + (t - 16) * 16) :
            (t < 20) ? (b1_b + (t - 18) * 16) : (v1_b + (t - 20) * 16);
        float4v bb = *(const float4v*)(bptr + quad * 4);
        float vb[4];
#pragma unroll
        for (int j = 0; j < 4; ++j) vb[j] = acc[t][j] + bb[j];

        if (t < 16) {              // w1: agent a = t>>1, slot base = (t&1)*4
            float q = qv[t >> 1];
            int base = (t & 1) * 4;
#pragma unroll
            for (int j = 0; j < 4; ++j) qacc[base + j] += q * fabsf(vb[j]);
        } else if (t < 18) {       // w_final
            int base = (t - 16) * 4;
#pragma unroll
            for (int j = 0; j < 4; ++j) wfv[base + j] = fabsf(vb[j]);
        } else if (t < 20) {       // b1
            int base = (t - 18) * 4;
#pragma unroll
            for (int j = 0; j < 4; ++j) b1v[base + j] = vb[j];
        } else {                   // V hidden: relu -> dot v2_W
            int ebase = (t - 20) * 16 + quad * 4;
#pragma unroll
            for (int j = 0; j < 4; ++j)
                svp += fmaxf(vb[j], 0.f) * v2_W[ebase + j];
        }
    }

    float mix = 0.f;
#pragma unroll
    for (int s = 0; s < 8; ++s) {
        float h = qacc[s] + b1v[s];
        h = h > 0.f ? h : (__expf(h) - 1.f);   // elu, alpha=1
        mix += h * wfv[s];
    }
    float tot = mix + svp;                      // partial over this quad's e-subset
    tot += __shfl_xor(tot, 16);                 // combine 4 quads (same batch row)
    tot += __shfl_xor(tot, 32);
    if (quad == 0) out[row] = tot + v2_b[0];
}

extern "C" void kernel_launch(void* const* d_in, const int* in_sizes, int n_in,
                              void* d_out, int out_size, void* d_ws, size_t ws_size,
                              hipStream_t stream) {
    const float* agent_qs = (const float*)d_in[0];
    const float* states   = (const float*)d_in[1];
    const float* w1_W = (const float*)d_in[2];
    const float* w1_b = (const float*)d_in[3];
    const float* wf_W = (const float*)d_in[4];
    const float* wf_b = (const float*)d_in[5];
    const float* b1_W = (const float*)d_in[6];
    const float* b1_b = (const float*)d_in[7];
    const float* v1_W = (const float*)d_in[8];
    const float* v1_b = (const float*)d_in[9];
    const float* v2_W = (const float*)d_in[10];
    const float* v2_b = (const float*)d_in[11];
    float* out = (float*)d_out;
    unsigned short* brep = (unsigned short*)d_ws;    // 180224 B of scratch

    repack_b<<<44, 256, 0, stream>>>(w1_W, wf_W, b1_W, v1_W, brep);
    qmix_main<<<1024, 256, 0, stream>>>(agent_qs, states, brep,
                                        w1_b, wf_b, b1_b, v1_b, v2_W, v2_b, out);
}